// Round 8
// baseline (3865.161 us; speedup 1.0000x reference)
//
#include <hip/hip_runtime.h>

#define N_USERS 100000
#define N_ITEMS 200000
#define N_NODES 300000
#define EMB 64
#define N_EDGES 9600000
#define BATCH 4096

// ---------------- CSR build ----------------
__global__ __launch_bounds__(256) void hist_kernel(const int* __restrict__ er, int* __restrict__ cnt) {
    int e = blockIdx.x * 256 + threadIdx.x;
    if (e < N_EDGES) atomicAdd(&cnt[er[e]], 1);
}

__global__ __launch_bounds__(1024) void scan1_kernel(const int* __restrict__ cnt, int* __restrict__ rp,
                                                     int* __restrict__ bsum) {
    __shared__ int s[1024];
    int t = threadIdx.x;
    int g = blockIdx.x * 1024 + t;
    int x = (g < N_NODES) ? cnt[g] : 0;
    s[t] = x;
    __syncthreads();
    #pragma unroll
    for (int off = 1; off < 1024; off <<= 1) {
        int add = (t >= off) ? s[t - off] : 0;
        __syncthreads();
        s[t] += add;
        __syncthreads();
    }
    if (g < N_NODES) rp[g] = s[t] - x;          // block-local exclusive prefix
    if (t == 1023) bsum[blockIdx.x] = s[1023];  // block total
}

__global__ __launch_bounds__(512) void scan2_kernel(int* __restrict__ bsum, int nb) {
    __shared__ int s[512];
    int t = threadIdx.x;
    int x = (t < nb) ? bsum[t] : 0;
    s[t] = x;
    __syncthreads();
    #pragma unroll
    for (int off = 1; off < 512; off <<= 1) {
        int add = (t >= off) ? s[t - off] : 0;
        __syncthreads();
        s[t] += add;
        __syncthreads();
    }
    if (t < nb) bsum[t] = s[t] - x;  // exclusive block offsets
}

__global__ __launch_bounds__(1024) void scan3_kernel(int* __restrict__ rp, const int* __restrict__ bsum) {
    int g = blockIdx.x * 1024 + threadIdx.x;
    if (g < N_NODES) rp[g] += bsum[blockIdx.x];
    if (g == 0) rp[N_NODES] = N_EDGES;
}

__global__ __launch_bounds__(256) void scatter_kernel(const int* __restrict__ er, const int* __restrict__ ec,
                                                      const float* __restrict__ ev, const int* __restrict__ rp,
                                                      int* __restrict__ fill, int* __restrict__ ccol,
                                                      float* __restrict__ cval) {
    int e = blockIdx.x * 256 + threadIdx.x;
    if (e >= N_EDGES) return;
    int r = er[e];
    int p = rp[r] + atomicAdd(&fill[r], 1);
    ccol[p] = ec[e];
    cval[p] = ev[e];
}

// ---------------- SpMM: neigh = A @ ego (one wave per row, lane = dim) ----------------
__global__ __launch_bounds__(256) void spmm_kernel(const int* __restrict__ rp, const int* __restrict__ ccol,
                                                   const float* __restrict__ cval, const float* __restrict__ ego,
                                                   float* __restrict__ neigh) {
    int w = (blockIdx.x * 256 + threadIdx.x) >> 6;
    int lane = threadIdx.x & 63;
    if (w >= N_NODES) return;
    int beg = rp[w], end = rp[w + 1];
    float a0 = 0.f, a1 = 0.f, a2 = 0.f, a3 = 0.f;
    int e = beg;
    for (; e + 4 <= end; e += 4) {
        int c0 = ccol[e], c1 = ccol[e + 1], c2 = ccol[e + 2], c3 = ccol[e + 3];
        float v0 = cval[e], v1 = cval[e + 1], v2 = cval[e + 2], v3 = cval[e + 3];
        a0 += v0 * ego[c0 * 64 + lane];
        a1 += v1 * ego[c1 * 64 + lane];
        a2 += v2 * ego[c2 * 64 + lane];
        a3 += v3 * ego[c3 * 64 + lane];
    }
    for (; e < end; ++e) a0 += cval[e] * ego[ccol[e] * 64 + lane];
    neigh[w * 64 + lane] = (a0 + a1) + (a2 + a3);
}

// ---------------- SpMM fallback: one wave per EDGE, float atomics (small-ws path) ----------------
__global__ __launch_bounds__(256) void spmm_atomic_kernel(const int* __restrict__ er, const int* __restrict__ ec,
                                                          const float* __restrict__ ev, const float* __restrict__ ego,
                                                          float* __restrict__ neigh) {
    int e = (blockIdx.x * 256 + threadIdx.x) >> 6;
    int lane = threadIdx.x & 63;
    if (e >= N_EDGES) return;
    int r = er[e], c = ec[e];
    float v = ev[e];
    atomicAdd(&neigh[(size_t)r * 64 + lane], v * ego[(size_t)c * 64 + lane]);
}

// ---------------- fused transform: ego = l2norm(lrelu(neigh@Wg + b + (ego*neigh)@Wb + b)) ----------------
__global__ __launch_bounds__(256) void transform_kernel(float* __restrict__ ego, const float* __restrict__ neigh,
                                                        const float* __restrict__ Wg, const float* __restrict__ bg,
                                                        const float* __restrict__ Wb, const float* __restrict__ bb) {
    __shared__ float sWg[64 * 64];
    __shared__ float sWb[64 * 64];
    __shared__ float sB[64];
    int t = threadIdx.x;
    for (int i = t; i < 4096; i += 256) { sWg[i] = Wg[i]; sWb[i] = Wb[i]; }
    if (t < 64) sB[t] = bg[t] + bb[t];
    __syncthreads();
    int lane = t & 63;
    int r0 = (blockIdx.x * 4 + (t >> 6)) * 2;  // 2 rows per wave
    int r1 = r0 + 1;
    float xs0 = neigh[r0 * 64 + lane];
    float xb0 = ego[r0 * 64 + lane] * xs0;
    float xs1 = neigh[r1 * 64 + lane];
    float xb1 = ego[r1 * 64 + lane] * xs1;
    float acc0 = sB[lane], acc1 = acc0;
    #pragma unroll
    for (int i = 0; i < 64; ++i) {
        float wg = sWg[i * 64 + lane];
        float wb = sWb[i * 64 + lane];
        acc0 += __shfl(xs0, i) * wg + __shfl(xb0, i) * wb;
        acc1 += __shfl(xs1, i) * wg + __shfl(xb1, i) * wb;
    }
    float y0 = acc0 > 0.f ? acc0 : 0.2f * acc0;
    float y1 = acc1 > 0.f ? acc1 : 0.2f * acc1;
    float ss0 = y0 * y0, ss1 = y1 * y1;
    #pragma unroll
    for (int off = 32; off >= 1; off >>= 1) {
        ss0 += __shfl_xor(ss0, off);
        ss1 += __shfl_xor(ss1, off);
    }
    float s0 = 1.f / fmaxf(sqrtf(ss0), 1e-12f);
    float s1 = 1.f / fmaxf(sqrtf(ss1), 1e-12f);
    ego[r0 * 64 + lane] = y0 * s0;
    ego[r1 * 64 + lane] = y1 * s1;
}

// ---------------- batch output gathers ----------------
__global__ __launch_bounds__(256) void gather0_kernel(const float* __restrict__ ue, const float* __restrict__ ie,
                                                      const int* __restrict__ users, const int* __restrict__ pos,
                                                      const int* __restrict__ neg, float* __restrict__ out) {
    int idx = blockIdx.x * 256 + threadIdx.x;
    int j = idx & 63, b = idx >> 6;
    float v;
    if (b < BATCH) v = ue[users[b] * 64 + j];
    else if (b < 2 * BATCH) v = ie[pos[b - BATCH] * 64 + j];
    else v = ie[neg[b - 2 * BATCH] * 64 + j];
    out[b * 256 + j] = v;
}

__global__ __launch_bounds__(256) void gatherk_kernel(const float* __restrict__ ego, const int* __restrict__ users,
                                                      const int* __restrict__ pos, const int* __restrict__ neg,
                                                      float* __restrict__ out, int seg) {
    int idx = blockIdx.x * 256 + threadIdx.x;
    int j = idx & 63, b = idx >> 6;
    int node;
    if (b < BATCH) node = users[b];
    else if (b < 2 * BATCH) node = N_USERS + pos[b - BATCH];
    else node = N_USERS + neg[b - 2 * BATCH];
    out[b * 256 + seg * 64 + j] = ego[node * 64 + j];
}

extern "C" void kernel_launch(void* const* d_in, const int* in_sizes, int n_in,
                              void* d_out, int out_size, void* d_ws, size_t ws_size,
                              hipStream_t stream) {
    const int*   edge_row  = (const int*)d_in[0];
    const int*   edge_col  = (const int*)d_in[1];
    const float* edge_val  = (const float*)d_in[2];
    const float* user_emb  = (const float*)d_in[3];
    const float* item_emb  = (const float*)d_in[4];
    const float* W_gc      = (const float*)d_in[5];
    const float* b_gc      = (const float*)d_in[6];
    const float* W_bi      = (const float*)d_in[7];
    const float* b_bi      = (const float*)d_in[8];
    const int*   users     = (const int*)d_in[9];
    const int*   pos_items = (const int*)d_in[10];
    const int*   neg_items = (const int*)d_in[11];
    float* out = (float*)d_out;
    (void)in_sizes; (void)n_in; (void)out_size;

    const size_t EGO_B   = (size_t)N_NODES * EMB * 4;   // 76.8 MB
    const size_t CSR_B   = (size_t)N_EDGES * 4;         // 38.4 MB each
    const size_t RP_B    = ((size_t)(N_NODES + 1) * 4 + 255) & ~(size_t)255;
    const size_t CNT_B   = ((size_t)N_NODES * 4 + 255) & ~(size_t)255;
    // CSR path footprint: 2*EGO + 2*CSR + rp + cnt + fill + bsum
    const size_t NEED_CSR = 2 * EGO_B + 2 * CSR_B + RP_B + 2 * CNT_B + 4096 + 4096;
    // atomic path footprint: 2*EGO only
    const bool use_csr = (ws_size >= NEED_CSR);

    char* base = (char*)d_ws;
    size_t off = 0;
    auto alloc = [&](size_t b) { void* p = base + off; off = (off + b + 255) & ~(size_t)255; return p; };
    float* ego   = (float*)alloc(EGO_B);
    float* neigh = (float*)alloc(EGO_B);
    int*   ccol  = nullptr;
    float* cval  = nullptr;
    int *rp = nullptr, *cnt = nullptr, *fill = nullptr, *bsum = nullptr;
    if (use_csr) {
        ccol = (int*)alloc(CSR_B);
        cval = (float*)alloc(CSR_B);
        rp   = (int*)alloc((size_t)(N_NODES + 1) * 4);
        cnt  = (int*)alloc((size_t)N_NODES * 4);
        fill = (int*)alloc((size_t)N_NODES * 4);
        bsum = (int*)alloc(4096);
    }

    // ego = concat(user_emb, item_emb)
    hipMemcpyAsync(ego, user_emb, (size_t)N_USERS * EMB * 4, hipMemcpyDeviceToDevice, stream);
    hipMemcpyAsync(ego + (size_t)N_USERS * EMB, item_emb, (size_t)N_ITEMS * EMB * 4, hipMemcpyDeviceToDevice, stream);

    if (use_csr) {
        hipMemsetAsync(cnt, 0, (size_t)N_NODES * 4, stream);
        hipMemsetAsync(fill, 0, (size_t)N_NODES * 4, stream);
        const int NB = (N_NODES + 1023) / 1024;  // 293
        hist_kernel<<<(N_EDGES + 255) / 256, 256, 0, stream>>>(edge_row, cnt);
        scan1_kernel<<<NB, 1024, 0, stream>>>(cnt, rp, bsum);
        scan2_kernel<<<1, 512, 0, stream>>>(bsum, NB);
        scan3_kernel<<<NB, 1024, 0, stream>>>(rp, bsum);
        scatter_kernel<<<(N_EDGES + 255) / 256, 256, 0, stream>>>(edge_row, edge_col, edge_val, rp, fill, ccol, cval);
    }

    gather0_kernel<<<(3 * BATCH * EMB) / 256, 256, 0, stream>>>(user_emb, item_emb, users, pos_items, neg_items, out);

    for (int k = 0; k < 3; ++k) {
        if (use_csr) {
            spmm_kernel<<<(N_NODES + 3) / 4, 256, 0, stream>>>(rp, ccol, cval, ego, neigh);
        } else {
            hipMemsetAsync(neigh, 0, EGO_B, stream);
            spmm_atomic_kernel<<<(N_EDGES + 3) / 4, 256, 0, stream>>>(edge_row, edge_col, edge_val, ego, neigh);
        }
        transform_kernel<<<(N_NODES + 7) / 8, 256, 0, stream>>>(ego, neigh,
                                                                W_gc + k * 4096, b_gc + k * 64,
                                                                W_bi + k * 4096, b_bi + k * 64);
        gatherk_kernel<<<(3 * BATCH * EMB) / 256, 256, 0, stream>>>(ego, users, pos_items, neg_items, out, k + 1);
    }
}

// Round 10
// 3582.710 us; speedup vs baseline: 1.0788x; 1.0788x over previous
//
#include <hip/hip_runtime.h>

#define N_USERS 100000
#define N_ITEMS 200000
#define N_NODES 300000
#define EMB 64
#define N_EDGES 9600000
#define BATCH 4096

// ---------------- CSR build ----------------
__global__ __launch_bounds__(256) void hist_kernel(const int4* __restrict__ er4, int* __restrict__ cnt) {
    int i = blockIdx.x * 256 + threadIdx.x;
    if (i >= N_EDGES / 4) return;
    int4 r = er4[i];
    atomicAdd(&cnt[r.x], 1);
    atomicAdd(&cnt[r.y], 1);
    atomicAdd(&cnt[r.z], 1);
    atomicAdd(&cnt[r.w], 1);
}

__global__ __launch_bounds__(1024) void scan1_kernel(const int* __restrict__ cnt, int* __restrict__ rp,
                                                     int* __restrict__ bsum) {
    __shared__ int s[1024];
    int t = threadIdx.x;
    int g = blockIdx.x * 1024 + t;
    int x = (g < N_NODES) ? cnt[g] : 0;
    s[t] = x;
    __syncthreads();
    #pragma unroll
    for (int off = 1; off < 1024; off <<= 1) {
        int add = (t >= off) ? s[t - off] : 0;
        __syncthreads();
        s[t] += add;
        __syncthreads();
    }
    if (g < N_NODES) rp[g] = s[t] - x;          // block-local exclusive prefix
    if (t == 1023) bsum[blockIdx.x] = s[1023];  // block total
}

__global__ __launch_bounds__(512) void scan2_kernel(int* __restrict__ bsum, int nb) {
    __shared__ int s[512];
    int t = threadIdx.x;
    int x = (t < nb) ? bsum[t] : 0;
    s[t] = x;
    __syncthreads();
    #pragma unroll
    for (int off = 1; off < 512; off <<= 1) {
        int add = (t >= off) ? s[t - off] : 0;
        __syncthreads();
        s[t] += add;
        __syncthreads();
    }
    if (t < nb) bsum[t] = s[t] - x;  // exclusive block offsets
}

__global__ __launch_bounds__(1024) void scan3_kernel(int* __restrict__ rp, const int* __restrict__ bsum) {
    int g = blockIdx.x * 1024 + threadIdx.x;
    if (g < N_NODES) rp[g] += bsum[blockIdx.x];
    if (g == 0) rp[N_NODES] = N_EDGES;
}

// packed (col, val) record: one 8B scattered store per edge, 2 edges/thread
__global__ __launch_bounds__(256) void scatter_kernel(const int2* __restrict__ er2, const int2* __restrict__ ec2,
                                                      const float2* __restrict__ ev2, const int* __restrict__ rp,
                                                      int* __restrict__ fill, int2* __restrict__ ccv) {
    int i = blockIdx.x * 256 + threadIdx.x;
    if (i >= N_EDGES / 2) return;
    int2 r = er2[i];
    int2 c = ec2[i];
    float2 v = ev2[i];
    int p0 = rp[r.x] + atomicAdd(&fill[r.x], 1);
    ccv[p0] = make_int2(c.x, __float_as_int(v.x));
    int p1 = rp[r.y] + atomicAdd(&fill[r.y], 1);
    ccv[p1] = make_int2(c.y, __float_as_int(v.y));
}

// ---------------- SpMM: neigh = A @ ego ----------------
// one wave per row; 16 lanes x float4 per edge; 4 edge-groups/wave; 2-deep unroll -> 8 gathers in flight
__global__ __launch_bounds__(256) void spmm_kernel(const int* __restrict__ rp, const int2* __restrict__ ccv,
                                                   const float4* __restrict__ ego4, float4* __restrict__ neigh4) {
    int w = (blockIdx.x * 256 + threadIdx.x) >> 6;
    int lane = threadIdx.x & 63;
    if (w >= N_NODES) return;
    int g = lane >> 4, sub = lane & 15;
    int beg = rp[w], end = rp[w + 1];
    float4 a0 = {0.f, 0.f, 0.f, 0.f}, a1 = {0.f, 0.f, 0.f, 0.f};
    int e = beg + g;
    for (; e + 4 < end; e += 8) {
        int2 r0 = ccv[e];
        int2 r1 = ccv[e + 4];
        float4 v0 = ego4[(size_t)r0.x * 16 + sub];
        float4 v1 = ego4[(size_t)r1.x * 16 + sub];
        float s0 = __int_as_float(r0.y), s1 = __int_as_float(r1.y);
        a0.x += s0 * v0.x; a0.y += s0 * v0.y; a0.z += s0 * v0.z; a0.w += s0 * v0.w;
        a1.x += s1 * v1.x; a1.y += s1 * v1.y; a1.z += s1 * v1.z; a1.w += s1 * v1.w;
    }
    for (; e < end; e += 4) {
        int2 r0 = ccv[e];
        float4 v0 = ego4[(size_t)r0.x * 16 + sub];
        float s0 = __int_as_float(r0.y);
        a0.x += s0 * v0.x; a0.y += s0 * v0.y; a0.z += s0 * v0.z; a0.w += s0 * v0.w;
    }
    a0.x += a1.x; a0.y += a1.y; a0.z += a1.z; a0.w += a1.w;
    // butterfly across the 4 groups (lanes ^16, ^32)
    a0.x += __shfl_xor(a0.x, 16); a0.y += __shfl_xor(a0.y, 16);
    a0.z += __shfl_xor(a0.z, 16); a0.w += __shfl_xor(a0.w, 16);
    a0.x += __shfl_xor(a0.x, 32); a0.y += __shfl_xor(a0.y, 32);
    a0.z += __shfl_xor(a0.z, 32); a0.w += __shfl_xor(a0.w, 32);
    if (g == 0) neigh4[(size_t)w * 16 + sub] = a0;
}

// ---------------- SpMM fallback: one wave per EDGE, float atomics (small-ws path) ----------------
__global__ __launch_bounds__(256) void spmm_atomic_kernel(const int* __restrict__ er, const int* __restrict__ ec,
                                                          const float* __restrict__ ev, const float* __restrict__ ego,
                                                          float* __restrict__ neigh) {
    int e = (blockIdx.x * 256 + threadIdx.x) >> 6;
    int lane = threadIdx.x & 63;
    if (e >= N_EDGES) return;
    int r = er[e], c = ec[e];
    float v = ev[e];
    atomicAdd(&neigh[(size_t)r * 64 + lane], v * ego[(size_t)c * 64 + lane]);
}

// ---------------- fused transform: ego = l2norm(lrelu(neigh@Wg + b + (ego*neigh)@Wb + b)) ----------------
__global__ __launch_bounds__(256) void transform_kernel(float* __restrict__ ego, const float* __restrict__ neigh,
                                                        const float* __restrict__ Wg, const float* __restrict__ bg,
                                                        const float* __restrict__ Wb, const float* __restrict__ bb) {
    __shared__ float sWg[64 * 64];
    __shared__ float sWb[64 * 64];
    __shared__ float sB[64];
    int t = threadIdx.x;
    for (int i = t; i < 4096; i += 256) { sWg[i] = Wg[i]; sWb[i] = Wb[i]; }
    if (t < 64) sB[t] = bg[t] + bb[t];
    __syncthreads();
    int lane = t & 63;
    int r0 = (blockIdx.x * 4 + (t >> 6)) * 2;  // 2 rows per wave
    int r1 = r0 + 1;
    float xs0 = neigh[r0 * 64 + lane];
    float xb0 = ego[r0 * 64 + lane] * xs0;
    float xs1 = neigh[r1 * 64 + lane];
    float xb1 = ego[r1 * 64 + lane] * xs1;
    float acc0 = sB[lane], acc1 = acc0;
    #pragma unroll
    for (int i = 0; i < 64; ++i) {
        float wg = sWg[i * 64 + lane];
        float wb = sWb[i * 64 + lane];
        acc0 += __shfl(xs0, i) * wg + __shfl(xb0, i) * wb;
        acc1 += __shfl(xs1, i) * wg + __shfl(xb1, i) * wb;
    }
    float y0 = acc0 > 0.f ? acc0 : 0.2f * acc0;
    float y1 = acc1 > 0.f ? acc1 : 0.2f * acc1;
    float ss0 = y0 * y0, ss1 = y1 * y1;
    #pragma unroll
    for (int off = 32; off >= 1; off >>= 1) {
        ss0 += __shfl_xor(ss0, off);
        ss1 += __shfl_xor(ss1, off);
    }
    float s0 = 1.f / fmaxf(sqrtf(ss0), 1e-12f);
    float s1 = 1.f / fmaxf(sqrtf(ss1), 1e-12f);
    ego[r0 * 64 + lane] = y0 * s0;
    ego[r1 * 64 + lane] = y1 * s1;
}

// ---------------- batch output gathers ----------------
__global__ __launch_bounds__(256) void gather0_kernel(const float* __restrict__ ue, const float* __restrict__ ie,
                                                      const int* __restrict__ users, const int* __restrict__ pos,
                                                      const int* __restrict__ neg, float* __restrict__ out) {
    int idx = blockIdx.x * 256 + threadIdx.x;
    int j = idx & 63, b = idx >> 6;
    float v;
    if (b < BATCH) v = ue[users[b] * 64 + j];
    else if (b < 2 * BATCH) v = ie[pos[b - BATCH] * 64 + j];
    else v = ie[neg[b - 2 * BATCH] * 64 + j];
    out[b * 256 + j] = v;
}

__global__ __launch_bounds__(256) void gatherk_kernel(const float* __restrict__ ego, const int* __restrict__ users,
                                                      const int* __restrict__ pos, const int* __restrict__ neg,
                                                      float* __restrict__ out, int seg) {
    int idx = blockIdx.x * 256 + threadIdx.x;
    int j = idx & 63, b = idx >> 6;
    int node;
    if (b < BATCH) node = users[b];
    else if (b < 2 * BATCH) node = N_USERS + pos[b - BATCH];
    else node = N_USERS + neg[b - 2 * BATCH];
    out[b * 256 + seg * 64 + j] = ego[node * 64 + j];
}

extern "C" void kernel_launch(void* const* d_in, const int* in_sizes, int n_in,
                              void* d_out, int out_size, void* d_ws, size_t ws_size,
                              hipStream_t stream) {
    const int*   edge_row  = (const int*)d_in[0];
    const int*   edge_col  = (const int*)d_in[1];
    const float* edge_val  = (const float*)d_in[2];
    const float* user_emb  = (const float*)d_in[3];
    const float* item_emb  = (const float*)d_in[4];
    const float* W_gc      = (const float*)d_in[5];
    const float* b_gc      = (const float*)d_in[6];
    const float* W_bi      = (const float*)d_in[7];
    const float* b_bi      = (const float*)d_in[8];
    const int*   users     = (const int*)d_in[9];
    const int*   pos_items = (const int*)d_in[10];
    const int*   neg_items = (const int*)d_in[11];
    float* out = (float*)d_out;
    (void)in_sizes; (void)n_in; (void)out_size;

    const size_t EGO_B   = (size_t)N_NODES * EMB * 4;   // 76.8 MB
    const size_t CCV_B   = (size_t)N_EDGES * 8;         // 76.8 MB packed records
    const size_t RP_B    = ((size_t)(N_NODES + 1) * 4 + 255) & ~(size_t)255;
    const size_t CNT_B   = ((size_t)N_NODES * 4 + 255) & ~(size_t)255;
    const size_t NEED_CSR = 2 * EGO_B + CCV_B + RP_B + 2 * CNT_B + 4096 + 4096;
    const bool use_csr = (ws_size >= NEED_CSR);

    char* base = (char*)d_ws;
    size_t off = 0;
    auto alloc = [&](size_t b) { void* p = base + off; off = (off + b + 255) & ~(size_t)255; return p; };
    float* ego   = (float*)alloc(EGO_B);
    float* neigh = (float*)alloc(EGO_B);
    int2*  ccv   = nullptr;
    int *rp = nullptr, *cnt = nullptr, *fill = nullptr, *bsum = nullptr;
    if (use_csr) {
        ccv  = (int2*)alloc(CCV_B);
        rp   = (int*)alloc((size_t)(N_NODES + 1) * 4);
        cnt  = (int*)alloc((size_t)N_NODES * 4);
        fill = (int*)alloc((size_t)N_NODES * 4);
        bsum = (int*)alloc(4096);
    }

    // ego = concat(user_emb, item_emb)
    hipMemcpyAsync(ego, user_emb, (size_t)N_USERS * EMB * 4, hipMemcpyDeviceToDevice, stream);
    hipMemcpyAsync(ego + (size_t)N_USERS * EMB, item_emb, (size_t)N_ITEMS * EMB * 4, hipMemcpyDeviceToDevice, stream);

    if (use_csr) {
        hipMemsetAsync(cnt, 0, (size_t)N_NODES * 4, stream);
        hipMemsetAsync(fill, 0, (size_t)N_NODES * 4, stream);
        const int NB = (N_NODES + 1023) / 1024;  // 293
        hist_kernel<<<(N_EDGES / 4 + 255) / 256, 256, 0, stream>>>((const int4*)edge_row, cnt);
        scan1_kernel<<<NB, 1024, 0, stream>>>(cnt, rp, bsum);
        scan2_kernel<<<1, 512, 0, stream>>>(bsum, NB);
        scan3_kernel<<<NB, 1024, 0, stream>>>(rp, bsum);
        scatter_kernel<<<(N_EDGES / 2 + 255) / 256, 256, 0, stream>>>((const int2*)edge_row, (const int2*)edge_col,
                                                                      (const float2*)edge_val, rp, fill, ccv);
    }

    gather0_kernel<<<(3 * BATCH * EMB) / 256, 256, 0, stream>>>(user_emb, item_emb, users, pos_items, neg_items, out);

    for (int k = 0; k < 3; ++k) {
        if (use_csr) {
            spmm_kernel<<<(N_NODES + 3) / 4, 256, 0, stream>>>(rp, ccv, (const float4*)ego, (float4*)neigh);
        } else {
            hipMemsetAsync(neigh, 0, EGO_B, stream);
            spmm_atomic_kernel<<<(N_EDGES + 3) / 4, 256, 0, stream>>>(edge_row, edge_col, edge_val, ego, neigh);
        }
        transform_kernel<<<(N_NODES + 7) / 8, 256, 0, stream>>>(ego, neigh,
                                                                W_gc + k * 4096, b_gc + k * 64,
                                                                W_bi + k * 4096, b_bi + k * 64);
        gatherk_kernel<<<(3 * BATCH * EMB) / 256, 256, 0, stream>>>(ego, users, pos_items, neg_items, out, k + 1);
    }
}

// Round 11
// 2598.018 us; speedup vs baseline: 1.4877x; 1.3790x over previous
//
#include <hip/hip_runtime.h>

#define N_USERS 100000
#define N_ITEMS 200000
#define N_NODES 300000
#define EMB 64
#define N_EDGES 9600000
#define BATCH 4096

// ---------------- CSR build ----------------
__global__ __launch_bounds__(256) void hist_kernel(const int4* __restrict__ er4, int* __restrict__ cnt) {
    int i = blockIdx.x * 256 + threadIdx.x;
    if (i >= N_EDGES / 4) return;
    int4 r = er4[i];
    atomicAdd(&cnt[r.x], 1);
    atomicAdd(&cnt[r.y], 1);
    atomicAdd(&cnt[r.z], 1);
    atomicAdd(&cnt[r.w], 1);
}

__global__ __launch_bounds__(1024) void scan1_kernel(const int* __restrict__ cnt, int* __restrict__ rp,
                                                     int* __restrict__ bsum) {
    __shared__ int s[1024];
    int t = threadIdx.x;
    int g = blockIdx.x * 1024 + t;
    int x = (g < N_NODES) ? cnt[g] : 0;
    s[t] = x;
    __syncthreads();
    #pragma unroll
    for (int off = 1; off < 1024; off <<= 1) {
        int add = (t >= off) ? s[t - off] : 0;
        __syncthreads();
        s[t] += add;
        __syncthreads();
    }
    if (g < N_NODES) rp[g] = s[t] - x;          // block-local exclusive prefix
    if (t == 1023) bsum[blockIdx.x] = s[1023];  // block total
}

__global__ __launch_bounds__(512) void scan2_kernel(int* __restrict__ bsum, int nb) {
    __shared__ int s[512];
    int t = threadIdx.x;
    int x = (t < nb) ? bsum[t] : 0;
    s[t] = x;
    __syncthreads();
    #pragma unroll
    for (int off = 1; off < 512; off <<= 1) {
        int add = (t >= off) ? s[t - off] : 0;
        __syncthreads();
        s[t] += add;
        __syncthreads();
    }
    if (t < nb) bsum[t] = s[t] - x;  // exclusive block offsets
}

__global__ __launch_bounds__(1024) void scan3_kernel(int* __restrict__ rp, const int* __restrict__ bsum) {
    int g = blockIdx.x * 1024 + threadIdx.x;
    if (g < N_NODES) rp[g] += bsum[blockIdx.x];
    if (g == 0) rp[N_NODES] = N_EDGES;
}

// packed (col, val) record: one 8B scattered store per edge, 2 edges/thread
__global__ __launch_bounds__(256) void scatter_kernel(const int2* __restrict__ er2, const int2* __restrict__ ec2,
                                                      const float2* __restrict__ ev2, const int* __restrict__ rp,
                                                      int* __restrict__ fill, int2* __restrict__ ccv) {
    int i = blockIdx.x * 256 + threadIdx.x;
    if (i >= N_EDGES / 2) return;
    int2 r = er2[i];
    int2 c = ec2[i];
    float2 v = ev2[i];
    int p0 = rp[r.x] + atomicAdd(&fill[r.x], 1);
    ccv[p0] = make_int2(c.x, __float_as_int(v.x));
    int p1 = rp[r.y] + atomicAdd(&fill[r.y], 1);
    ccv[p1] = make_int2(c.y, __float_as_int(v.y));
}

// ---------------- SpMM: neigh = A @ ego ----------------
// one wave per row; 16 lanes x float4 per edge; 4 edge-groups/wave; 2-deep unroll -> 8 gathers in flight
__global__ __launch_bounds__(256) void spmm_kernel(const int* __restrict__ rp, const int2* __restrict__ ccv,
                                                   const float4* __restrict__ ego4, float4* __restrict__ neigh4) {
    int w = (blockIdx.x * 256 + threadIdx.x) >> 6;
    int lane = threadIdx.x & 63;
    if (w >= N_NODES) return;
    int g = lane >> 4, sub = lane & 15;
    int beg = rp[w], end = rp[w + 1];
    float4 a0 = {0.f, 0.f, 0.f, 0.f}, a1 = {0.f, 0.f, 0.f, 0.f};
    int e = beg + g;
    for (; e + 4 < end; e += 8) {
        int2 r0 = ccv[e];
        int2 r1 = ccv[e + 4];
        float4 v0 = ego4[(size_t)r0.x * 16 + sub];
        float4 v1 = ego4[(size_t)r1.x * 16 + sub];
        float s0 = __int_as_float(r0.y), s1 = __int_as_float(r1.y);
        a0.x += s0 * v0.x; a0.y += s0 * v0.y; a0.z += s0 * v0.z; a0.w += s0 * v0.w;
        a1.x += s1 * v1.x; a1.y += s1 * v1.y; a1.z += s1 * v1.z; a1.w += s1 * v1.w;
    }
    for (; e < end; e += 4) {
        int2 r0 = ccv[e];
        float4 v0 = ego4[(size_t)r0.x * 16 + sub];
        float s0 = __int_as_float(r0.y);
        a0.x += s0 * v0.x; a0.y += s0 * v0.y; a0.z += s0 * v0.z; a0.w += s0 * v0.w;
    }
    a0.x += a1.x; a0.y += a1.y; a0.z += a1.z; a0.w += a1.w;
    // butterfly across the 4 groups (lanes ^16, ^32)
    a0.x += __shfl_xor(a0.x, 16); a0.y += __shfl_xor(a0.y, 16);
    a0.z += __shfl_xor(a0.z, 16); a0.w += __shfl_xor(a0.w, 16);
    a0.x += __shfl_xor(a0.x, 32); a0.y += __shfl_xor(a0.y, 32);
    a0.z += __shfl_xor(a0.z, 32); a0.w += __shfl_xor(a0.w, 32);
    if (g == 0) neigh4[(size_t)w * 16 + sub] = a0;
}

// ---------------- SpMM fallback: one wave per EDGE, float atomics (small-ws path) ----------------
__global__ __launch_bounds__(256) void spmm_atomic_kernel(const int* __restrict__ er, const int* __restrict__ ec,
                                                          const float* __restrict__ ev, const float* __restrict__ ego,
                                                          float* __restrict__ neigh) {
    int e = (blockIdx.x * 256 + threadIdx.x) >> 6;
    int lane = threadIdx.x & 63;
    if (e >= N_EDGES) return;
    int r = er[e], c = ec[e];
    float v = ev[e];
    atomicAdd(&neigh[(size_t)r * 64 + lane], v * ego[(size_t)c * 64 + lane]);
}

// ---------------- fused transform: ego = l2norm(lrelu(neigh@Wg + b + (ego*neigh)@Wb + b)) ----------------
// lane = row (64 rows/block), 2 waves split the 64 output dims (32 j each).
// W[i][j] is wave-uniform -> scalar loads; x from padded LDS (bank = (lane+i)%32, conflict-free).
__global__ __launch_bounds__(128) void transform_kernel(float* __restrict__ ego, const float* __restrict__ neigh,
                                                        const float* __restrict__ Wg, const float* __restrict__ bg,
                                                        const float* __restrict__ Wb, const float* __restrict__ bb) {
    __shared__ float sN[64 * 65];
    __shared__ float sE[64 * 65];
    __shared__ float sRed[2 * 64];
    int t = threadIdx.x;
    int rowBase = blockIdx.x * 64;
    // stage 64 rows of neigh & ego (coalesced float4 reads, scalar LDS writes into padded layout)
    for (int it = 0; it < 8; ++it) {
        int idx = it * 128 + t;   // float4 index within 64x16
        int r = idx >> 4;
        int c4 = idx & 15;
        if (rowBase + r < N_NODES) {
            float4 vn = ((const float4*)neigh)[(size_t)(rowBase + r) * 16 + c4];
            float4 ve = ((const float4*)ego)[(size_t)(rowBase + r) * 16 + c4];
            int base = r * 65 + c4 * 4;
            sN[base + 0] = vn.x; sN[base + 1] = vn.y; sN[base + 2] = vn.z; sN[base + 3] = vn.w;
            sE[base + 0] = ve.x; sE[base + 1] = ve.y; sE[base + 2] = ve.z; sE[base + 3] = ve.w;
        }
    }
    __syncthreads();
    int lane = t & 63;
    int wid = __builtin_amdgcn_readfirstlane(t >> 6);  // force SGPR -> W indices uniform
    int jofs = wid * 32;
    int row = rowBase + lane;
    float acc[32];
    #pragma unroll
    for (int j = 0; j < 32; ++j) acc[j] = bg[jofs + j] + bb[jofs + j];
    for (int i = 0; i < 64; ++i) {
        float xn = sN[lane * 65 + i];
        float xb = xn * sE[lane * 65 + i];
        const float* __restrict__ wgp = Wg + i * 64 + jofs;
        const float* __restrict__ wbp = Wb + i * 64 + jofs;
        #pragma unroll
        for (int j = 0; j < 32; ++j) {
            acc[j] += xn * wgp[j] + xb * wbp[j];
        }
    }
    // leaky relu + per-row partial sum of squares
    float ss = 0.f;
    #pragma unroll
    for (int j = 0; j < 32; ++j) {
        float y = acc[j] > 0.f ? acc[j] : 0.2f * acc[j];
        acc[j] = y;
        ss += y * y;
    }
    sRed[wid * 64 + lane] = ss;
    __syncthreads();
    float tot = sRed[lane] + sRed[64 + lane];
    float s = 1.f / fmaxf(sqrtf(tot), 1e-12f);
    if (row < N_NODES) {
        #pragma unroll
        for (int j = 0; j < 32; ++j) ego[(size_t)row * 64 + jofs + j] = acc[j] * s;
    }
}

// ---------------- batch output gathers ----------------
__global__ __launch_bounds__(256) void gather0_kernel(const float* __restrict__ ue, const float* __restrict__ ie,
                                                      const int* __restrict__ users, const int* __restrict__ pos,
                                                      const int* __restrict__ neg, float* __restrict__ out) {
    int idx = blockIdx.x * 256 + threadIdx.x;
    int j = idx & 63, b = idx >> 6;
    float v;
    if (b < BATCH) v = ue[users[b] * 64 + j];
    else if (b < 2 * BATCH) v = ie[pos[b - BATCH] * 64 + j];
    else v = ie[neg[b - 2 * BATCH] * 64 + j];
    out[b * 256 + j] = v;
}

__global__ __launch_bounds__(256) void gatherk_kernel(const float* __restrict__ ego, const int* __restrict__ users,
                                                      const int* __restrict__ pos, const int* __restrict__ neg,
                                                      float* __restrict__ out, int seg) {
    int idx = blockIdx.x * 256 + threadIdx.x;
    int j = idx & 63, b = idx >> 6;
    int node;
    if (b < BATCH) node = users[b];
    else if (b < 2 * BATCH) node = N_USERS + pos[b - BATCH];
    else node = N_USERS + neg[b - 2 * BATCH];
    out[b * 256 + seg * 64 + j] = ego[node * 64 + j];
}

extern "C" void kernel_launch(void* const* d_in, const int* in_sizes, int n_in,
                              void* d_out, int out_size, void* d_ws, size_t ws_size,
                              hipStream_t stream) {
    const int*   edge_row  = (const int*)d_in[0];
    const int*   edge_col  = (const int*)d_in[1];
    const float* edge_val  = (const float*)d_in[2];
    const float* user_emb  = (const float*)d_in[3];
    const float* item_emb  = (const float*)d_in[4];
    const float* W_gc      = (const float*)d_in[5];
    const float* b_gc      = (const float*)d_in[6];
    const float* W_bi      = (const float*)d_in[7];
    const float* b_bi      = (const float*)d_in[8];
    const int*   users     = (const int*)d_in[9];
    const int*   pos_items = (const int*)d_in[10];
    const int*   neg_items = (const int*)d_in[11];
    float* out = (float*)d_out;
    (void)in_sizes; (void)n_in; (void)out_size;

    const size_t EGO_B   = (size_t)N_NODES * EMB * 4;   // 76.8 MB
    const size_t CCV_B   = (size_t)N_EDGES * 8;         // 76.8 MB packed records
    const size_t RP_B    = ((size_t)(N_NODES + 1) * 4 + 255) & ~(size_t)255;
    const size_t CNT_B   = ((size_t)N_NODES * 4 + 255) & ~(size_t)255;
    const size_t NEED_CSR = 2 * EGO_B + CCV_B + RP_B + 2 * CNT_B + 4096 + 4096;
    const bool use_csr = (ws_size >= NEED_CSR);

    char* base = (char*)d_ws;
    size_t off = 0;
    auto alloc = [&](size_t b) { void* p = base + off; off = (off + b + 255) & ~(size_t)255; return p; };
    float* ego   = (float*)alloc(EGO_B);
    float* neigh = (float*)alloc(EGO_B);
    int2*  ccv   = nullptr;
    int *rp = nullptr, *cnt = nullptr, *fill = nullptr, *bsum = nullptr;
    if (use_csr) {
        ccv  = (int2*)alloc(CCV_B);
        rp   = (int*)alloc((size_t)(N_NODES + 1) * 4);
        cnt  = (int*)alloc((size_t)N_NODES * 4);
        fill = (int*)alloc((size_t)N_NODES * 4);
        bsum = (int*)alloc(4096);
    }

    // ego = concat(user_emb, item_emb)
    hipMemcpyAsync(ego, user_emb, (size_t)N_USERS * EMB * 4, hipMemcpyDeviceToDevice, stream);
    hipMemcpyAsync(ego + (size_t)N_USERS * EMB, item_emb, (size_t)N_ITEMS * EMB * 4, hipMemcpyDeviceToDevice, stream);

    if (use_csr) {
        hipMemsetAsync(cnt, 0, (size_t)N_NODES * 4, stream);
        hipMemsetAsync(fill, 0, (size_t)N_NODES * 4, stream);
        const int NB = (N_NODES + 1023) / 1024;  // 293
        hist_kernel<<<(N_EDGES / 4 + 255) / 256, 256, 0, stream>>>((const int4*)edge_row, cnt);
        scan1_kernel<<<NB, 1024, 0, stream>>>(cnt, rp, bsum);
        scan2_kernel<<<1, 512, 0, stream>>>(bsum, NB);
        scan3_kernel<<<NB, 1024, 0, stream>>>(rp, bsum);
        scatter_kernel<<<(N_EDGES / 2 + 255) / 256, 256, 0, stream>>>((const int2*)edge_row, (const int2*)edge_col,
                                                                      (const float2*)edge_val, rp, fill, ccv);
    }

    gather0_kernel<<<(3 * BATCH * EMB) / 256, 256, 0, stream>>>(user_emb, item_emb, users, pos_items, neg_items, out);

    const int TGRID = (N_NODES + 63) / 64;  // 4688
    for (int k = 0; k < 3; ++k) {
        if (use_csr) {
            spmm_kernel<<<(N_NODES + 3) / 4, 256, 0, stream>>>(rp, ccv, (const float4*)ego, (float4*)neigh);
        } else {
            hipMemsetAsync(neigh, 0, EGO_B, stream);
            spmm_atomic_kernel<<<(N_EDGES + 3) / 4, 256, 0, stream>>>(edge_row, edge_col, edge_val, ego, neigh);
        }
        transform_kernel<<<TGRID, 128, 0, stream>>>(ego, neigh,
                                                    W_gc + k * 4096, b_gc + k * 64,
                                                    W_bi + k * 4096, b_bi + k * 64);
        gatherk_kernel<<<(3 * BATCH * EMB) / 256, 256, 0, stream>>>(ego, users, pos_items, neg_items, out, k + 1);
    }
}

// Round 12
// 2538.380 us; speedup vs baseline: 1.5227x; 1.0235x over previous
//
#include <hip/hip_runtime.h>

#define N_USERS 100000
#define N_ITEMS 200000
#define N_NODES 300000
#define EMB 64
#define N_EDGES 9600000
#define BATCH 4096

// ---------------- CSR build ----------------
__global__ __launch_bounds__(256) void hist_kernel(const int4* __restrict__ er4, int* __restrict__ cnt) {
    int i = blockIdx.x * 256 + threadIdx.x;
    if (i >= N_EDGES / 4) return;
    int4 r = er4[i];
    atomicAdd(&cnt[r.x], 1);
    atomicAdd(&cnt[r.y], 1);
    atomicAdd(&cnt[r.z], 1);
    atomicAdd(&cnt[r.w], 1);
}

__global__ __launch_bounds__(1024) void scan1_kernel(const int* __restrict__ cnt, int* __restrict__ rp,
                                                     int* __restrict__ bsum) {
    __shared__ int s[1024];
    int t = threadIdx.x;
    int g = blockIdx.x * 1024 + t;
    int x = (g < N_NODES) ? cnt[g] : 0;
    s[t] = x;
    __syncthreads();
    #pragma unroll
    for (int off = 1; off < 1024; off <<= 1) {
        int add = (t >= off) ? s[t - off] : 0;
        __syncthreads();
        s[t] += add;
        __syncthreads();
    }
    if (g < N_NODES) rp[g] = s[t] - x;          // block-local exclusive prefix
    if (t == 1023) bsum[blockIdx.x] = s[1023];  // block total
}

__global__ __launch_bounds__(512) void scan2_kernel(int* __restrict__ bsum, int nb) {
    __shared__ int s[512];
    int t = threadIdx.x;
    int x = (t < nb) ? bsum[t] : 0;
    s[t] = x;
    __syncthreads();
    #pragma unroll
    for (int off = 1; off < 512; off <<= 1) {
        int add = (t >= off) ? s[t - off] : 0;
        __syncthreads();
        s[t] += add;
        __syncthreads();
    }
    if (t < nb) bsum[t] = s[t] - x;  // exclusive block offsets
}

__global__ __launch_bounds__(1024) void scan3_kernel(int* __restrict__ rp, const int* __restrict__ bsum) {
    int g = blockIdx.x * 1024 + threadIdx.x;
    if (g < N_NODES) rp[g] += bsum[blockIdx.x];
    if (g == 0) rp[N_NODES] = N_EDGES;
}

// packed (col, val) record: one 8B scattered store per edge, 4 edges/thread for MLP
__global__ __launch_bounds__(256) void scatter_kernel(const int4* __restrict__ er4, const int4* __restrict__ ec4,
                                                      const float4* __restrict__ ev4, const int* __restrict__ rp,
                                                      int* __restrict__ fill, int2* __restrict__ ccv) {
    int i = blockIdx.x * 256 + threadIdx.x;
    if (i >= N_EDGES / 4) return;
    int4 r = er4[i];
    int4 c = ec4[i];
    float4 v = ev4[i];
    int p0 = rp[r.x] + atomicAdd(&fill[r.x], 1);
    ccv[p0] = make_int2(c.x, __float_as_int(v.x));
    int p1 = rp[r.y] + atomicAdd(&fill[r.y], 1);
    ccv[p1] = make_int2(c.y, __float_as_int(v.y));
    int p2 = rp[r.z] + atomicAdd(&fill[r.z], 1);
    ccv[p2] = make_int2(c.z, __float_as_int(v.z));
    int p3 = rp[r.w] + atomicAdd(&fill[r.w], 1);
    ccv[p3] = make_int2(c.w, __float_as_int(v.w));
}

// ---------------- SpMM: neigh = A @ ego ----------------
// one wave per row; 16 lanes x float4 per edge; 4 edge-groups/wave; 4-deep unroll -> 16 gathers in flight
__global__ __launch_bounds__(256) void spmm_kernel(const int* __restrict__ rp, const int2* __restrict__ ccv,
                                                   const float4* __restrict__ ego4, float4* __restrict__ neigh4) {
    int w = (blockIdx.x * 256 + threadIdx.x) >> 6;
    int lane = threadIdx.x & 63;
    if (w >= N_NODES) return;
    int g = lane >> 4, sub = lane & 15;
    int beg = rp[w], end = rp[w + 1];
    float4 a0 = {0.f, 0.f, 0.f, 0.f}, a1 = {0.f, 0.f, 0.f, 0.f};
    float4 a2 = {0.f, 0.f, 0.f, 0.f}, a3 = {0.f, 0.f, 0.f, 0.f};
    int e = beg + g;
    for (; e + 12 < end; e += 16) {
        int2 r0 = ccv[e];
        int2 r1 = ccv[e + 4];
        int2 r2 = ccv[e + 8];
        int2 r3 = ccv[e + 12];
        float4 v0 = ego4[(size_t)r0.x * 16 + sub];
        float4 v1 = ego4[(size_t)r1.x * 16 + sub];
        float4 v2 = ego4[(size_t)r2.x * 16 + sub];
        float4 v3 = ego4[(size_t)r3.x * 16 + sub];
        float s0 = __int_as_float(r0.y), s1 = __int_as_float(r1.y);
        float s2 = __int_as_float(r2.y), s3 = __int_as_float(r3.y);
        a0.x += s0 * v0.x; a0.y += s0 * v0.y; a0.z += s0 * v0.z; a0.w += s0 * v0.w;
        a1.x += s1 * v1.x; a1.y += s1 * v1.y; a1.z += s1 * v1.z; a1.w += s1 * v1.w;
        a2.x += s2 * v2.x; a2.y += s2 * v2.y; a2.z += s2 * v2.z; a2.w += s2 * v2.w;
        a3.x += s3 * v3.x; a3.y += s3 * v3.y; a3.z += s3 * v3.z; a3.w += s3 * v3.w;
    }
    for (; e < end; e += 4) {
        int2 r0 = ccv[e];
        float4 v0 = ego4[(size_t)r0.x * 16 + sub];
        float s0 = __int_as_float(r0.y);
        a0.x += s0 * v0.x; a0.y += s0 * v0.y; a0.z += s0 * v0.z; a0.w += s0 * v0.w;
    }
    a0.x += a1.x; a0.y += a1.y; a0.z += a1.z; a0.w += a1.w;
    a2.x += a3.x; a2.y += a3.y; a2.z += a3.z; a2.w += a3.w;
    a0.x += a2.x; a0.y += a2.y; a0.z += a2.z; a0.w += a2.w;
    // butterfly across the 4 groups (lanes ^16, ^32)
    a0.x += __shfl_xor(a0.x, 16); a0.y += __shfl_xor(a0.y, 16);
    a0.z += __shfl_xor(a0.z, 16); a0.w += __shfl_xor(a0.w, 16);
    a0.x += __shfl_xor(a0.x, 32); a0.y += __shfl_xor(a0.y, 32);
    a0.z += __shfl_xor(a0.z, 32); a0.w += __shfl_xor(a0.w, 32);
    if (g == 0) neigh4[(size_t)w * 16 + sub] = a0;
}

// ---------------- SpMM fallback: one wave per EDGE, float atomics (small-ws path) ----------------
__global__ __launch_bounds__(256) void spmm_atomic_kernel(const int* __restrict__ er, const int* __restrict__ ec,
                                                          const float* __restrict__ ev, const float* __restrict__ ego,
                                                          float* __restrict__ neigh) {
    int e = (blockIdx.x * 256 + threadIdx.x) >> 6;
    int lane = threadIdx.x & 63;
    if (e >= N_EDGES) return;
    int r = er[e], c = ec[e];
    float v = ev[e];
    atomicAdd(&neigh[(size_t)r * 64 + lane], v * ego[(size_t)c * 64 + lane]);
}

// ---------------- fused transform: ego = l2norm(lrelu(neigh@Wg + b + (ego*neigh)@Wb + b)) ----------------
// lane = row (64 rows/block), 2 waves split the 64 output dims (32 j each).
// W[i][j] is wave-uniform -> scalar loads; x from padded LDS (bank = (lane+i)%32, conflict-free).
__global__ __launch_bounds__(128) void transform_kernel(float* __restrict__ ego, const float* __restrict__ neigh,
                                                        const float* __restrict__ Wg, const float* __restrict__ bg,
                                                        const float* __restrict__ Wb, const float* __restrict__ bb) {
    __shared__ float sN[64 * 65];
    __shared__ float sE[64 * 65];
    __shared__ float sRed[2 * 64];
    int t = threadIdx.x;
    int rowBase = blockIdx.x * 64;
    // stage 64 rows of neigh & ego (coalesced float4 reads, scalar LDS writes into padded layout)
    for (int it = 0; it < 8; ++it) {
        int idx = it * 128 + t;   // float4 index within 64x16
        int r = idx >> 4;
        int c4 = idx & 15;
        if (rowBase + r < N_NODES) {
            float4 vn = ((const float4*)neigh)[(size_t)(rowBase + r) * 16 + c4];
            float4 ve = ((const float4*)ego)[(size_t)(rowBase + r) * 16 + c4];
            int base = r * 65 + c4 * 4;
            sN[base + 0] = vn.x; sN[base + 1] = vn.y; sN[base + 2] = vn.z; sN[base + 3] = vn.w;
            sE[base + 0] = ve.x; sE[base + 1] = ve.y; sE[base + 2] = ve.z; sE[base + 3] = ve.w;
        }
    }
    __syncthreads();
    int lane = t & 63;
    int wid = __builtin_amdgcn_readfirstlane(t >> 6);  // force SGPR -> W indices uniform
    int jofs = wid * 32;
    int row = rowBase + lane;
    float acc[32];
    #pragma unroll
    for (int j = 0; j < 32; ++j) acc[j] = bg[jofs + j] + bb[jofs + j];
    for (int i = 0; i < 64; ++i) {
        float xn = sN[lane * 65 + i];
        float xb = xn * sE[lane * 65 + i];
        const float* __restrict__ wgp = Wg + i * 64 + jofs;
        const float* __restrict__ wbp = Wb + i * 64 + jofs;
        #pragma unroll
        for (int j = 0; j < 32; ++j) {
            acc[j] += xn * wgp[j] + xb * wbp[j];
        }
    }
    // leaky relu + per-row partial sum of squares
    float ss = 0.f;
    #pragma unroll
    for (int j = 0; j < 32; ++j) {
        float y = acc[j] > 0.f ? acc[j] : 0.2f * acc[j];
        acc[j] = y;
        ss += y * y;
    }
    sRed[wid * 64 + lane] = ss;
    __syncthreads();
    float tot = sRed[lane] + sRed[64 + lane];
    float s = 1.f / fmaxf(sqrtf(tot), 1e-12f);
    if (row < N_NODES) {
        #pragma unroll
        for (int j = 0; j < 32; ++j) ego[(size_t)row * 64 + jofs + j] = acc[j] * s;
    }
}

// ---------------- batch output gathers ----------------
__global__ __launch_bounds__(256) void gather0_kernel(const float* __restrict__ ue, const float* __restrict__ ie,
                                                      const int* __restrict__ users, const int* __restrict__ pos,
                                                      const int* __restrict__ neg, float* __restrict__ out) {
    int idx = blockIdx.x * 256 + threadIdx.x;
    int j = idx & 63, b = idx >> 6;
    float v;
    if (b < BATCH) v = ue[users[b] * 64 + j];
    else if (b < 2 * BATCH) v = ie[pos[b - BATCH] * 64 + j];
    else v = ie[neg[b - 2 * BATCH] * 64 + j];
    out[b * 256 + j] = v;
}

__global__ __launch_bounds__(256) void gatherk_kernel(const float* __restrict__ ego, const int* __restrict__ users,
                                                      const int* __restrict__ pos, const int* __restrict__ neg,
                                                      float* __restrict__ out, int seg) {
    int idx = blockIdx.x * 256 + threadIdx.x;
    int j = idx & 63, b = idx >> 6;
    int node;
    if (b < BATCH) node = users[b];
    else if (b < 2 * BATCH) node = N_USERS + pos[b - BATCH];
    else node = N_USERS + neg[b - 2 * BATCH];
    out[b * 256 + seg * 64 + j] = ego[node * 64 + j];
}

extern "C" void kernel_launch(void* const* d_in, const int* in_sizes, int n_in,
                              void* d_out, int out_size, void* d_ws, size_t ws_size,
                              hipStream_t stream) {
    const int*   edge_row  = (const int*)d_in[0];
    const int*   edge_col  = (const int*)d_in[1];
    const float* edge_val  = (const float*)d_in[2];
    const float* user_emb  = (const float*)d_in[3];
    const float* item_emb  = (const float*)d_in[4];
    const float* W_gc      = (const float*)d_in[5];
    const float* b_gc      = (const float*)d_in[6];
    const float* W_bi      = (const float*)d_in[7];
    const float* b_bi      = (const float*)d_in[8];
    const int*   users     = (const int*)d_in[9];
    const int*   pos_items = (const int*)d_in[10];
    const int*   neg_items = (const int*)d_in[11];
    float* out = (float*)d_out;
    (void)in_sizes; (void)n_in; (void)out_size;

    const size_t EGO_B   = (size_t)N_NODES * EMB * 4;   // 76.8 MB
    const size_t CCV_B   = (size_t)N_EDGES * 8;         // 76.8 MB packed records
    const size_t RP_B    = ((size_t)(N_NODES + 1) * 4 + 255) & ~(size_t)255;
    const size_t CNT_B   = ((size_t)N_NODES * 4 + 255) & ~(size_t)255;
    const size_t NEED_CSR = 2 * EGO_B + CCV_B + RP_B + 2 * CNT_B + 4096 + 4096;
    const bool use_csr = (ws_size >= NEED_CSR);

    char* base = (char*)d_ws;
    size_t off = 0;
    auto alloc = [&](size_t b) { void* p = base + off; off = (off + b + 255) & ~(size_t)255; return p; };
    float* ego   = (float*)alloc(EGO_B);
    float* neigh = (float*)alloc(EGO_B);
    int2*  ccv   = nullptr;
    int *rp = nullptr, *cnt = nullptr, *fill = nullptr, *bsum = nullptr;
    if (use_csr) {
        ccv  = (int2*)alloc(CCV_B);
        rp   = (int*)alloc((size_t)(N_NODES + 1) * 4);
        cnt  = (int*)alloc((size_t)N_NODES * 4);
        fill = (int*)alloc((size_t)N_NODES * 4);
        bsum = (int*)alloc(4096);
    }

    // ego = concat(user_emb, item_emb)
    hipMemcpyAsync(ego, user_emb, (size_t)N_USERS * EMB * 4, hipMemcpyDeviceToDevice, stream);
    hipMemcpyAsync(ego + (size_t)N_USERS * EMB, item_emb, (size_t)N_ITEMS * EMB * 4, hipMemcpyDeviceToDevice, stream);

    if (use_csr) {
        hipMemsetAsync(cnt, 0, (size_t)N_NODES * 4, stream);
        hipMemsetAsync(fill, 0, (size_t)N_NODES * 4, stream);
        const int NB = (N_NODES + 1023) / 1024;  // 293
        hist_kernel<<<(N_EDGES / 4 + 255) / 256, 256, 0, stream>>>((const int4*)edge_row, cnt);
        scan1_kernel<<<NB, 1024, 0, stream>>>(cnt, rp, bsum);
        scan2_kernel<<<1, 512, 0, stream>>>(bsum, NB);
        scan3_kernel<<<NB, 1024, 0, stream>>>(rp, bsum);
        scatter_kernel<<<(N_EDGES / 4 + 255) / 256, 256, 0, stream>>>((const int4*)edge_row, (const int4*)edge_col,
                                                                      (const float4*)edge_val, rp, fill, ccv);
    }

    gather0_kernel<<<(3 * BATCH * EMB) / 256, 256, 0, stream>>>(user_emb, item_emb, users, pos_items, neg_items, out);

    const int TGRID = (N_NODES + 63) / 64;  // 4688
    for (int k = 0; k < 3; ++k) {
        if (use_csr) {
            spmm_kernel<<<(N_NODES + 3) / 4, 256, 0, stream>>>(rp, ccv, (const float4*)ego, (float4*)neigh);
        } else {
            hipMemsetAsync(neigh, 0, EGO_B, stream);
            spmm_atomic_kernel<<<(N_EDGES + 3) / 4, 256, 0, stream>>>(edge_row, edge_col, edge_val, ego, neigh);
        }
        transform_kernel<<<TGRID, 128, 0, stream>>>(ego, neigh,
                                                    W_gc + k * 4096, b_gc + k * 64,
                                                    W_bi + k * 4096, b_bi + k * 64);
        gatherk_kernel<<<(3 * BATCH * EMB) / 256, 256, 0, stream>>>(ego, users, pos_items, neg_items, out, k + 1);
    }
}